// Round 11
// baseline (8003.065 us; speedup 1.0000x reference)
//
#include <hip/hip_runtime.h>
#include <hip/hip_bf16.h>

#define NF 128
#define RBF 20

using short8 = __attribute__((ext_vector_type(8))) short;
using f32x4  = __attribute__((ext_vector_type(4))) float;

__device__ __forceinline__ float sspf(float v) {
    return fmaxf(v, 0.f) + log1pf(__expf(-fabsf(v))) - 0.69314718055994531f;
}
__device__ __forceinline__ unsigned short f2bf(float f) {
    union { float f; unsigned u; } v; v.f = f;
    unsigned r = v.u + 0x7fffu + ((v.u >> 16) & 1u);
    return (unsigned short)(r >> 16);
}
__device__ __forceinline__ float bf2f(unsigned short s) {
    union { unsigned u; float f; } v; v.u = ((unsigned)s) << 16;
    return v.f;
}

// ---------------------------------------------------------------------------
// Counting sort by idx_i only.
// ---------------------------------------------------------------------------
__global__ void hist1_kernel(const int* __restrict__ idx, int* __restrict__ deg, int E)
{
    for (int e = blockIdx.x * blockDim.x + threadIdx.x; e < E;
         e += gridDim.x * blockDim.x)
        atomicAdd(&deg[idx[e]], 1);
}

__global__ void scanA1_kernel(const int* __restrict__ deg, int* __restrict__ loc,
                              int* __restrict__ parts, int NN)
{
    const int tid = threadIdx.x;
    const int base = blockIdx.x * 2048;
    __shared__ int tsum[256];
    int v[8]; int s = 0;
    #pragma unroll
    for (int r = 0; r < 8; ++r) {
        const int idx = base + tid * 8 + r;
        v[r] = (idx < NN) ? deg[idx] : 0;
        s += v[r];
    }
    tsum[tid] = s;
    __syncthreads();
    #pragma unroll
    for (int d = 1; d < 256; d <<= 1) {
        const int add = (tid >= d) ? tsum[tid - d] : 0;
        __syncthreads();
        tsum[tid] += add;
        __syncthreads();
    }
    int run = tsum[tid] - s;
    #pragma unroll
    for (int r = 0; r < 8; ++r) {
        const int idx = base + tid * 8 + r;
        if (idx < NN) loc[idx] = run;
        run += v[r];
    }
    if (tid == 0) parts[blockIdx.x] = tsum[255];
}

__global__ void scanB1_kernel(int* __restrict__ parts, int NB)
{
    __shared__ int p[64];
    const int t = threadIdx.x;
    p[t] = (t < NB) ? parts[t] : 0;
    __syncthreads();
    #pragma unroll
    for (int d = 1; d < 64; d <<= 1) {
        const int add = (t >= d) ? p[t - d] : 0;
        __syncthreads();
        p[t] += add;
        __syncthreads();
    }
    parts[t] = (t > 0) ? p[t - 1] : 0;
}

__global__ void scanC1_kernel(const int* __restrict__ loc, const int* __restrict__ parts,
                              int* __restrict__ rowp, int* __restrict__ cur, int NN)
{
    for (int i = blockIdx.x * blockDim.x + threadIdx.x; i < NN;
         i += gridDim.x * blockDim.x) {
        const int v = loc[i] + parts[i >> 11];
        rowp[i] = v;
        cur[i]  = v;
    }
}

__global__ void scatter1_kernel(const int* __restrict__ idx, int* __restrict__ cur,
                                int* __restrict__ ord, int E)
{
    for (int e = blockIdx.x * blockDim.x + threadIdx.x; e < E;
         e += gridDim.x * blockDim.x) {
        const int p = atomicAdd(&cur[idx[e]], 1);
        ord[p] = e;
    }
}

// ---------------------------------------------------------------------------
// Hybrid edge kernel (512 thr = 8 waves, 16 cols/wave). Block owns 32 nodes
// (i-sorted). Per 64-edge tile:
//   phase1 (MFMA): h = ssp(f @ W1 + b1)
//   phase2 (MFMA): wij = h @ W2 (+b2 later)
//   stage g = yf[j] rows; per-thread: M = bf16(wv*g) -> LDS;
//     y-side: conv_y[j] += xf_own[i]*wv via fp32 atomics (count halved)
//   phase3 (MFMA): accS += S @ M  (one-hot selector) -> conv_x plain stores
// ---------------------------------------------------------------------------
__global__ __launch_bounds__(512, 2)
void edge_hybrid_kernel(const float* __restrict__ f_ij,
                        const float* __restrict__ rcut,
                        const int* __restrict__ idx_i,
                        const int* __restrict__ idx_j,
                        const float* __restrict__ Wf1,
                        const float* __restrict__ bf1,
                        const float* __restrict__ Wf2,
                        const float* __restrict__ bf2v,
                        const unsigned short* __restrict__ xf,
                        const unsigned short* __restrict__ yf,
                        const int* __restrict__ ord,
                        const int* __restrict__ rowp,
                        float* __restrict__ conv_x,
                        float* __restrict__ conv_y,
                        int NN, int E)
{
    const int tid = threadIdx.x;
    const int l = tid & 63, w = tid >> 6;
    const int lr = l & 15, lk = l >> 4;
    const int wcol = w * 16 + lr;

    __shared__ unsigned short f16[64 * 40];     // 5.1 KB
    __shared__ unsigned short Ash[64 * NF];     // 16 KB: h (swz) then g
    __shared__ unsigned short M_s[64 * 137];    // 17.5 KB
    __shared__ unsigned short xown[32 * NF];    // 8 KB: own xf rows
    __shared__ int ni_s[64];
    __shared__ int jo_s[64];
    __shared__ float rc_s[64];

    // persistent weight fragments (16 cols per wave)
    short8 b1fr;
    #pragma unroll
    for (int j = 0; j < 8; ++j) {
        const int k = lk * 8 + j;
        b1fr[j] = (k < RBF) ? (short)f2bf(Wf1[k * NF + wcol]) : (short)0;
    }
    short8 b2fr[4];
    #pragma unroll
    for (int kb = 0; kb < 4; ++kb)
        #pragma unroll
        for (int j = 0; j < 8; ++j)
            b2fr[kb][j] = (short)f2bf(Wf2[(size_t)(kb * 32 + lk * 8 + j) * NF + wcol]);
    const float b1c = bf1[wcol];
    const float b2c = bf2v[wcol];

    const int n0 = blockIdx.x * 32;
    const int eb = rowp[n0];
    const int ee = (n0 + 32 < NN) ? rowp[n0 + 32] : E;
    const int nt = (ee - eb + 63) >> 6;

    // stage own xf rows [n0, n0+32): 2048 uints
    #pragma unroll
    for (int u = 0; u < 4; ++u) {
        const int tt = u * 512 + tid;
        const int row = tt >> 6, cp = tt & 63;
        unsigned v = 0;
        if (n0 + row < NN)
            v = reinterpret_cast<const unsigned*>(xf)[(size_t)(n0 + row) * 64 + cp];
        reinterpret_cast<unsigned*>(xown)[tt] = v;
    }

    f32x4 accS[2] = {};    // nodes [n0+rb2*16 ...], col wcol

    for (int t = 0; t < nt; ++t) {
        const int p0 = eb + t * 64;
        __syncthreads();

        if (tid < 64) {
            const int p = p0 + tid;
            const bool val = p < ee;
            const int e = val ? ord[p] : 0;
            ni_s[tid] = val ? idx_i[e] : -1;
            jo_s[tid] = val ? idx_j[e] * NF : 0;
            rc_s[tid] = val ? rcut[e] : 0.f;
        }
        #pragma unroll
        for (int s4 = 0; s4 < 4; ++s4) {
            const int tt = s4 * 512 + tid;
            const int row = tt >> 5, k = tt & 31;
            const int p = p0 + row;
            float v = 0.f;
            if (k < RBF && p < ee) v = f_ij[(size_t)ord[p] * RBF + k];
            f16[row * 40 + k] = f2bf(v);
        }
        __syncthreads();

        // phase 1: h = ssp(f @ W1 + b1)
        f32x4 acc1[4] = {};
        #pragma unroll
        for (int rb = 0; rb < 4; ++rb) {
            const short8 a = *reinterpret_cast<const short8*>(
                &f16[(rb * 16 + lr) * 40 + lk * 8]);
            acc1[rb] = __builtin_amdgcn_mfma_f32_16x16x32_bf16(a, b1fr, acc1[rb], 0, 0, 0);
        }
        #pragma unroll
        for (int rb = 0; rb < 4; ++rb)
            #pragma unroll
            for (int q = 0; q < 4; ++q) {
                const int e = rb * 16 + lk * 4 + q;
                const float hv = sspf(acc1[rb][q] + b1c);
                Ash[e * NF + (wcol ^ ((e & 7) << 3))] = f2bf(hv);
            }
        __syncthreads();

        // phase 2: wij = h @ W2
        f32x4 acc2[4] = {};
        #pragma unroll
        for (int rb = 0; rb < 4; ++rb) {
            short8 a[4];
            #pragma unroll
            for (int kb = 0; kb < 4; ++kb) {
                const int e  = rb * 16 + lr;
                const int k0 = kb * 32 + lk * 8;
                a[kb] = *reinterpret_cast<const short8*>(
                    &Ash[e * NF + (k0 ^ ((e & 7) << 3))]);
            }
            #pragma unroll
            for (int kb = 0; kb < 4; ++kb)
                acc2[rb] = __builtin_amdgcn_mfma_f32_16x16x32_bf16(
                    a[kb], b2fr[kb], acc2[rb], 0, 0, 0);
        }
        __syncthreads();            // h reads done -> Ash reusable

        // stage g = yf[j] rows: 4096 uints
        #pragma unroll
        for (int u = 0; u < 8; ++u) {
            const int tt = u * 512 + tid;
            const int slot = tt >> 6, cp = tt & 63;
            reinterpret_cast<unsigned*>(Ash)[tt] =
                reinterpret_cast<const unsigned*>(yf)[(jo_s[slot] >> 1) + cp];
        }
        __syncthreads();

        // per-thread: M write (x-side) + atomic (y-side)
        #pragma unroll
        for (int rb = 0; rb < 4; ++rb)
            #pragma unroll
            for (int q = 0; q < 4; ++q) {
                const int e = rb * 16 + lk * 4 + q;
                const float wv = (acc2[rb][q] + b2c) * rc_s[e];
                const float g  = bf2f(Ash[e * NF + wcol]);
                M_s[e * 137 + wcol] = f2bf(wv * g);
                int oi = ni_s[e] - n0; oi = oi < 0 ? 0 : oi;
                const float xo = bf2f(xown[oi * NF + wcol]);
                unsafeAtomicAdd(&conv_y[(size_t)jo_s[e] + wcol], xo * wv);
            }
        __syncthreads();

        // phase 3: accS += S @ M  (selector one-hot)
        #pragma unroll
        for (int kb2 = 0; kb2 < 2; ++kb2) {
            short8 bm;
            #pragma unroll
            for (int j = 0; j < 8; ++j)
                bm[j] = (short)M_s[(kb2 * 32 + lk * 8 + j) * 137 + wcol];
            #pragma unroll
            for (int rb2 = 0; rb2 < 2; ++rb2) {
                const int node = n0 + rb2 * 16 + lr;
                short8 as;
                #pragma unroll
                for (int j = 0; j < 8; ++j)
                    as[j] = (ni_s[kb2 * 32 + lk * 8 + j] == node)
                            ? (short)0x3F80 : (short)0;
                accS[rb2] = __builtin_amdgcn_mfma_f32_16x16x32_bf16(
                    as, bm, accS[rb2], 0, 0, 0);
            }
        }
    }

    // conv_x rows [n0, n0+32): written once, plain stores
    #pragma unroll
    for (int rb2 = 0; rb2 < 2; ++rb2)
        #pragma unroll
        for (int q = 0; q < 4; ++q) {
            const int n = n0 + rb2 * 16 + lk * 4 + q;
            if (n < NN) conv_x[(size_t)n * NF + wcol] = accS[rb2][q];
        }
}

// ---------------------------------------------------------------------------
// Projection (persistent): out_bf16 = in @ W (bias-free) + zero conv_y
// ---------------------------------------------------------------------------
__global__ __launch_bounds__(256, 2)
void proj_mfma_kernel(const float* in0, const float* in1,
                      const float* __restrict__ W0, const float* __restrict__ W1p,
                      unsigned short* o0, unsigned short* o1,
                      float* __restrict__ conv_y, int N, int nTiles)
{
    const float* in = blockIdx.y ? in1 : in0;
    const float* W  = blockIdx.y ? W1p : W0;
    unsigned short* out = blockIdx.y ? o1 : o0;

    const int tid = threadIdx.x;
    const int l = tid & 63, w = tid >> 6;
    const int lr = l & 15, lk = l >> 4;
    const int wcol0 = w * 32;

    __shared__ unsigned short Ahi[64 * NF];

    short8 bfr[4][2];
    #pragma unroll
    for (int kb = 0; kb < 4; ++kb)
        #pragma unroll
        for (int cb = 0; cb < 2; ++cb) {
            const int col = wcol0 + cb * 16 + lr;
            #pragma unroll
            for (int j = 0; j < 8; ++j)
                bfr[kb][cb][j] = (short)f2bf(W[(size_t)(kb * 32 + lk * 8 + j) * NF + col]);
        }

    for (int tile = blockIdx.x; tile < nTiles; tile += gridDim.x) {
        const int n0 = tile * 64;
        __syncthreads();
        #pragma unroll
        for (int s = 0; s < 32; ++s) {
            const int t = s * 256 + tid;
            const int row = t >> 7, cc = t & (NF - 1);
            const float v = (n0 + row < N) ? in[(size_t)(n0 + row) * NF + cc] : 0.f;
            Ahi[row * NF + (cc ^ ((row & 7) << 3))] = f2bf(v);
        }
        // zero conv_y rows [n0+32*y, n0+32*y+32)
        {
            const float4 z = {0.f, 0.f, 0.f, 0.f};
            const int rbase = n0 + 32 * blockIdx.y;
            #pragma unroll
            for (int s = 0; s < 4; ++s) {
                const int t = s * 256 + tid;
                const int row = rbase + (t >> 5);
                if (row < N)
                    *reinterpret_cast<float4*>(&conv_y[(size_t)row * NF + (t & 31) * 4]) = z;
            }
        }
        __syncthreads();

        f32x4 acc[4][2] = {};
        #pragma unroll
        for (int rb = 0; rb < 4; ++rb) {
            short8 a[4];
            #pragma unroll
            for (int kb = 0; kb < 4; ++kb) {
                const int e  = rb * 16 + lr;
                const int k0 = kb * 32 + lk * 8;
                a[kb] = *reinterpret_cast<const short8*>(&Ahi[e * NF + (k0 ^ ((e & 7) << 3))]);
            }
            #pragma unroll
            for (int cb = 0; cb < 2; ++cb)
                #pragma unroll
                for (int kb = 0; kb < 4; ++kb)
                    acc[rb][cb] = __builtin_amdgcn_mfma_f32_16x16x32_bf16(
                        a[kb], bfr[kb][cb], acc[rb][cb], 0, 0, 0);
        }

        #pragma unroll
        for (int rb = 0; rb < 4; ++rb)
            #pragma unroll
            for (int cb = 0; cb < 2; ++cb) {
                const int col = wcol0 + cb * 16 + lr;
                #pragma unroll
                for (int q = 0; q < 4; ++q) {
                    const int n = n0 + rb * 16 + lk * 4 + q;
                    if (n < N) out[(size_t)n * NF + col] = f2bf(acc[rb][cb][q]);
                }
            }
    }
}

// ---------------------------------------------------------------------------
// Fused output MLP (persistent): out = ssp(conv @ W1 + b1) @ W2 + b2
// split-bf16 (hi/lo) A for near-fp32 precision.
// ---------------------------------------------------------------------------
__global__ __launch_bounds__(256, 2)
void out_fused_kernel(const float* conv0, const float* conv1,
                      const float* __restrict__ W10, const float* __restrict__ W11,
                      const float* __restrict__ b10, const float* __restrict__ b11,
                      const float* __restrict__ W20, const float* __restrict__ W21,
                      const float* __restrict__ b20, const float* __restrict__ b21,
                      float* o0, float* o1, int N, int nTiles)
{
    const float* in = blockIdx.y ? conv1 : conv0;
    const float* W1 = blockIdx.y ? W11 : W10;
    const float* b1 = blockIdx.y ? b11 : b10;
    const float* W2 = blockIdx.y ? W21 : W20;
    const float* b2 = blockIdx.y ? b21 : b20;
    float* out      = blockIdx.y ? o1  : o0;

    const int tid = threadIdx.x;
    const int l = tid & 63, w = tid >> 6;
    const int lr = l & 15, lk = l >> 4;
    const int wcol0 = w * 32;

    __shared__ unsigned short Ahi[64 * NF];
    __shared__ unsigned short Alo[64 * NF];

    short8 w1fr[4][2], w2fr[4][2];
    #pragma unroll
    for (int kb = 0; kb < 4; ++kb)
        #pragma unroll
        for (int cb = 0; cb < 2; ++cb) {
            const int col = wcol0 + cb * 16 + lr;
            #pragma unroll
            for (int j = 0; j < 8; ++j) {
                const size_t kk = (size_t)(kb * 32 + lk * 8 + j) * NF + col;
                w1fr[kb][cb][j] = (short)f2bf(W1[kk]);
                w2fr[kb][cb][j] = (short)f2bf(W2[kk]);
            }
        }
    const float b1c0 = b1[wcol0 + lr], b1c1 = b1[wcol0 + 16 + lr];
    const float b2c0 = b2[wcol0 + lr], b2c1 = b2[wcol0 + 16 + lr];

    for (int tile = blockIdx.x; tile < nTiles; tile += gridDim.x) {
        const int n0 = tile * 64;
        __syncthreads();
        #pragma unroll
        for (int s = 0; s < 32; ++s) {
            const int t = s * 256 + tid;
            const int row = t >> 7, cc = t & (NF - 1);
            const float v = (n0 + row < N) ? in[(size_t)(n0 + row) * NF + cc] : 0.f;
            const unsigned short hi = f2bf(v);
            const int idx = row * NF + (cc ^ ((row & 7) << 3));
            Ahi[idx] = hi;
            Alo[idx] = f2bf(v - bf2f(hi));
        }
        __syncthreads();

        f32x4 acc1[4][2] = {};
        #pragma unroll
        for (int rb = 0; rb < 4; ++rb) {
            short8 ah[4], al[4];
            #pragma unroll
            for (int kb = 0; kb < 4; ++kb) {
                const int e  = rb * 16 + lr;
                const int k0 = kb * 32 + lk * 8;
                const int idx = e * NF + (k0 ^ ((e & 7) << 3));
                ah[kb] = *reinterpret_cast<const short8*>(&Ahi[idx]);
                al[kb] = *reinterpret_cast<const short8*>(&Alo[idx]);
            }
            #pragma unroll
            for (int cb = 0; cb < 2; ++cb)
                #pragma unroll
                for (int kb = 0; kb < 4; ++kb) {
                    acc1[rb][cb] = __builtin_amdgcn_mfma_f32_16x16x32_bf16(
                        ah[kb], w1fr[kb][cb], acc1[rb][cb], 0, 0, 0);
                    acc1[rb][cb] = __builtin_amdgcn_mfma_f32_16x16x32_bf16(
                        al[kb], w1fr[kb][cb], acc1[rb][cb], 0, 0, 0);
                }
        }
        __syncthreads();

        #pragma unroll
        for (int rb = 0; rb < 4; ++rb)
            #pragma unroll
            for (int cb = 0; cb < 2; ++cb) {
                const int col = wcol0 + cb * 16 + lr;
                #pragma unroll
                for (int q = 0; q < 4; ++q) {
                    const int e = rb * 16 + lk * 4 + q;
                    const float hv = sspf(acc1[rb][cb][q] + (cb ? b1c1 : b1c0));
                    const unsigned short hi = f2bf(hv);
                    const int idx = e * NF + (col ^ ((e & 7) << 3));
                    Ahi[idx] = hi;
                    Alo[idx] = f2bf(hv - bf2f(hi));
                }
            }
        __syncthreads();

        f32x4 acc2[4][2] = {};
        #pragma unroll
        for (int rb = 0; rb < 4; ++rb) {
            short8 ah[4], al[4];
            #pragma unroll
            for (int kb = 0; kb < 4; ++kb) {
                const int e  = rb * 16 + lr;
                const int k0 = kb * 32 + lk * 8;
                const int idx = e * NF + (k0 ^ ((e & 7) << 3));
                ah[kb] = *reinterpret_cast<const short8*>(&Ahi[idx]);
                al[kb] = *reinterpret_cast<const short8*>(&Alo[idx]);
            }
            #pragma unroll
            for (int cb = 0; cb < 2; ++cb)
                #pragma unroll
                for (int kb = 0; kb < 4; ++kb) {
                    acc2[rb][cb] = __builtin_amdgcn_mfma_f32_16x16x32_bf16(
                        ah[kb], w2fr[kb][cb], acc2[rb][cb], 0, 0, 0);
                    acc2[rb][cb] = __builtin_amdgcn_mfma_f32_16x16x32_bf16(
                        al[kb], w2fr[kb][cb], acc2[rb][cb], 0, 0, 0);
                }
        }

        #pragma unroll
        for (int rb = 0; rb < 4; ++rb)
            #pragma unroll
            for (int cb = 0; cb < 2; ++cb) {
                const int col = wcol0 + cb * 16 + lr;
                #pragma unroll
                for (int q = 0; q < 4; ++q) {
                    const int n = n0 + rb * 16 + lk * 4 + q;
                    if (n < N)
                        out[(size_t)n * NF + col] = acc2[rb][cb][q] + (cb ? b2c1 : b2c0);
                }
            }
    }
}

extern "C" void kernel_launch(void* const* d_in, const int* in_sizes, int n_in,
                              void* d_out, int out_size, void* d_ws, size_t ws_size,
                              hipStream_t stream)
{
    const float* x    = (const float*)d_in[0];
    const float* y    = (const float*)d_in[1];
    const float* f_ij = (const float*)d_in[2];
    const float* rcut = (const float*)d_in[3];
    const int* idx_i  = (const int*)d_in[4];
    const int* idx_j  = (const int*)d_in[5];
    const float* W_in2f   = (const float*)d_in[6];
    const float* W_in2f_y = (const float*)d_in[7];
    const float* Wf1 = (const float*)d_in[8];
    const float* bf1 = (const float*)d_in[9];
    const float* Wf2 = (const float*)d_in[10];
    const float* bf2 = (const float*)d_in[11];
    const float* Wx1 = (const float*)d_in[12];
    const float* bx1 = (const float*)d_in[13];
    const float* Wx2 = (const float*)d_in[14];
    const float* bx2 = (const float*)d_in[15];
    const float* Wy1 = (const float*)d_in[16];
    const float* by1 = (const float*)d_in[17];
    const float* Wy2 = (const float*)d_in[18];
    const float* by2 = (const float*)d_in[19];

    const int N = in_sizes[0] / NF;
    const int E = in_sizes[4];
    const size_t NNF = (size_t)N * NF;

    unsigned short* xf = (unsigned short*)d_out;
    unsigned short* yf = xf + NNF;
    float* ox = (float*)d_out;
    float* oy = ox + NNF;

    // sort scratch in upper half of d_out (dead before out_fused writes)
    int* sb    = (int*)((char*)d_out + 4 * NNF);
    int* deg   = sb;
    int* loc   = sb + N;
    int* rowp  = sb + 2 * N;
    int* cur   = sb + 3 * N;
    int* parts = sb + 4 * N;          // 64 ints
    int* ord   = sb + 4 * N + 64;     // E ints

    float* conv_x = (float*)d_ws;
    float* conv_y = conv_x + NNF;

    const int NB = (N + 2047) / 2048;
    const int nodeTiles = (N + 63) / 64;
    const int passBlocks = (N + 31) / 32;

    hipMemsetAsync(deg, 0, (size_t)N * sizeof(int), stream);

    proj_mfma_kernel<<<dim3(1024, 2), 256, 0, stream>>>(
        x, y, W_in2f, W_in2f_y, xf, yf, conv_y, N, nodeTiles);

    hist1_kernel<<<1024, 256, 0, stream>>>(idx_i, deg, E);
    scanA1_kernel<<<NB, 256, 0, stream>>>(deg, loc, parts, N);
    scanB1_kernel<<<1, 64, 0, stream>>>(parts, NB);
    scanC1_kernel<<<128, 256, 0, stream>>>(loc, parts, rowp, cur, N);
    scatter1_kernel<<<1024, 256, 0, stream>>>(idx_i, cur, ord, E);

    edge_hybrid_kernel<<<passBlocks, 512, 0, stream>>>(
        f_ij, rcut, idx_i, idx_j, Wf1, bf1, Wf2, bf2, xf, yf,
        ord, rowp, conv_x, conv_y, N, E);

    out_fused_kernel<<<dim3(1024, 2), 256, 0, stream>>>(
        conv_x, conv_y, Wx1, Wy1, bx1, by1, Wx2, Wy2, bx2, by2,
        ox, oy, N, nodeTiles);
}

// Round 12
// 992.182 us; speedup vs baseline: 8.0661x; 8.0661x over previous
//
#include <hip/hip_runtime.h>
#include <hip/hip_bf16.h>

#define NF 128
#define RBF 20

using short8 = __attribute__((ext_vector_type(8))) short;
using f32x4  = __attribute__((ext_vector_type(4))) float;

__device__ __forceinline__ float sspf(float v) {
    return fmaxf(v, 0.f) + log1pf(__expf(-fabsf(v))) - 0.69314718055994531f;
}
__device__ __forceinline__ unsigned short f2bf(float f) {
    union { float f; unsigned u; } v; v.f = f;
    unsigned r = v.u + 0x7fffu + ((v.u >> 16) & 1u);
    return (unsigned short)(r >> 16);
}
__device__ __forceinline__ float bf2f(unsigned short s) {
    union { unsigned u; float f; } v; v.u = ((unsigned)s) << 16;
    return v.f;
}

// ---------------------------------------------------------------------------
// Counting sort by idx_i only.
// ---------------------------------------------------------------------------
__global__ void hist1_kernel(const int* __restrict__ idx, int* __restrict__ deg, int E)
{
    for (int e = blockIdx.x * blockDim.x + threadIdx.x; e < E;
         e += gridDim.x * blockDim.x)
        atomicAdd(&deg[idx[e]], 1);
}

__global__ void scanA1_kernel(const int* __restrict__ deg, int* __restrict__ loc,
                              int* __restrict__ parts, int NN)
{
    const int tid = threadIdx.x;
    const int base = blockIdx.x * 2048;
    __shared__ int tsum[256];
    int v[8]; int s = 0;
    #pragma unroll
    for (int r = 0; r < 8; ++r) {
        const int idx = base + tid * 8 + r;
        v[r] = (idx < NN) ? deg[idx] : 0;
        s += v[r];
    }
    tsum[tid] = s;
    __syncthreads();
    #pragma unroll
    for (int d = 1; d < 256; d <<= 1) {
        const int add = (tid >= d) ? tsum[tid - d] : 0;
        __syncthreads();
        tsum[tid] += add;
        __syncthreads();
    }
    int run = tsum[tid] - s;
    #pragma unroll
    for (int r = 0; r < 8; ++r) {
        const int idx = base + tid * 8 + r;
        if (idx < NN) loc[idx] = run;
        run += v[r];
    }
    if (tid == 0) parts[blockIdx.x] = tsum[255];
}

__global__ void scanB1_kernel(int* __restrict__ parts, int NB)
{
    __shared__ int p[64];
    const int t = threadIdx.x;
    p[t] = (t < NB) ? parts[t] : 0;
    __syncthreads();
    #pragma unroll
    for (int d = 1; d < 64; d <<= 1) {
        const int add = (t >= d) ? p[t - d] : 0;
        __syncthreads();
        p[t] += add;
        __syncthreads();
    }
    parts[t] = (t > 0) ? p[t - 1] : 0;
}

__global__ void scanC1_kernel(const int* __restrict__ loc, const int* __restrict__ parts,
                              int* __restrict__ rowp, int* __restrict__ cur, int NN)
{
    for (int i = blockIdx.x * blockDim.x + threadIdx.x; i < NN;
         i += gridDim.x * blockDim.x) {
        const int v = loc[i] + parts[i >> 11];
        rowp[i] = v;
        cur[i]  = v;
    }
}

__global__ void scatter1_kernel(const int* __restrict__ idx, int* __restrict__ cur,
                                int* __restrict__ ord, int E)
{
    for (int e = blockIdx.x * blockDim.x + threadIdx.x; e < E;
         e += gridDim.x * blockDim.x) {
        const int p = atomicAdd(&cur[idx[e]], 1);
        ord[p] = e;
    }
}

// ---------------------------------------------------------------------------
// Hybrid edge kernel (512 thr = 8 waves, 16 cols/wave). Block owns 32 nodes
// (i-sorted). Per 64-edge tile:
//   phase1 (MFMA): h = ssp(f @ W1 + b1)
//   phase2 (MFMA): wij = h @ W2 (+b2 later)
//   stage g = yf[j] rows; per-thread: M = bf16(wv*g) -> LDS;
//     y-side: conv_y[j] += xf_own[i]*wv via fp32 atomics — VALID SLOTS ONLY
//   phase3 (MFMA): accS += S @ M  (one-hot selector) -> conv_x plain stores
// ---------------------------------------------------------------------------
__global__ __launch_bounds__(512, 2)
void edge_hybrid_kernel(const float* __restrict__ f_ij,
                        const float* __restrict__ rcut,
                        const int* __restrict__ idx_i,
                        const int* __restrict__ idx_j,
                        const float* __restrict__ Wf1,
                        const float* __restrict__ bf1,
                        const float* __restrict__ Wf2,
                        const float* __restrict__ bf2v,
                        const unsigned short* __restrict__ xf,
                        const unsigned short* __restrict__ yf,
                        const int* __restrict__ ord,
                        const int* __restrict__ rowp,
                        float* __restrict__ conv_x,
                        float* __restrict__ conv_y,
                        int NN, int E)
{
    const int tid = threadIdx.x;
    const int l = tid & 63, w = tid >> 6;
    const int lr = l & 15, lk = l >> 4;
    const int wcol = w * 16 + lr;

    __shared__ unsigned short f16[64 * 40];     // 5.1 KB
    __shared__ unsigned short Ash[64 * NF];     // 16 KB: h (swz) then g
    __shared__ unsigned short M_s[64 * 137];    // 17.5 KB
    __shared__ unsigned short xown[32 * NF];    // 8 KB: own xf rows
    __shared__ int ni_s[64];
    __shared__ int jo_s[64];
    __shared__ float rc_s[64];

    // persistent weight fragments (16 cols per wave)
    short8 b1fr;
    #pragma unroll
    for (int j = 0; j < 8; ++j) {
        const int k = lk * 8 + j;
        b1fr[j] = (k < RBF) ? (short)f2bf(Wf1[k * NF + wcol]) : (short)0;
    }
    short8 b2fr[4];
    #pragma unroll
    for (int kb = 0; kb < 4; ++kb)
        #pragma unroll
        for (int j = 0; j < 8; ++j)
            b2fr[kb][j] = (short)f2bf(Wf2[(size_t)(kb * 32 + lk * 8 + j) * NF + wcol]);
    const float b1c = bf1[wcol];
    const float b2c = bf2v[wcol];

    const int n0 = blockIdx.x * 32;
    const int eb = rowp[n0];
    const int ee = (n0 + 32 < NN) ? rowp[n0 + 32] : E;
    const int nt = (ee - eb + 63) >> 6;

    // stage own xf rows [n0, n0+32): 2048 uints
    #pragma unroll
    for (int u = 0; u < 4; ++u) {
        const int tt = u * 512 + tid;
        const int row = tt >> 6, cp = tt & 63;
        unsigned v = 0;
        if (n0 + row < NN)
            v = reinterpret_cast<const unsigned*>(xf)[(size_t)(n0 + row) * 64 + cp];
        reinterpret_cast<unsigned*>(xown)[tt] = v;
    }

    f32x4 accS[2] = {};    // nodes [n0+rb2*16 ...], col wcol

    for (int t = 0; t < nt; ++t) {
        const int p0 = eb + t * 64;
        const int cnt = ee - p0;             // valid slots this tile
        __syncthreads();

        if (tid < 64) {
            const int p = p0 + tid;
            const bool val = p < ee;
            const int e = val ? ord[p] : 0;
            ni_s[tid] = val ? idx_i[e] : -1;
            jo_s[tid] = val ? idx_j[e] * NF : 0;
            rc_s[tid] = val ? rcut[e] : 0.f;
        }
        #pragma unroll
        for (int s4 = 0; s4 < 4; ++s4) {
            const int tt = s4 * 512 + tid;
            const int row = tt >> 5, k = tt & 31;
            const int p = p0 + row;
            float v = 0.f;
            if (k < RBF && p < ee) v = f_ij[(size_t)ord[p] * RBF + k];
            f16[row * 40 + k] = f2bf(v);
        }
        __syncthreads();

        // phase 1: h = ssp(f @ W1 + b1)
        f32x4 acc1[4] = {};
        #pragma unroll
        for (int rb = 0; rb < 4; ++rb) {
            const short8 a = *reinterpret_cast<const short8*>(
                &f16[(rb * 16 + lr) * 40 + lk * 8]);
            acc1[rb] = __builtin_amdgcn_mfma_f32_16x16x32_bf16(a, b1fr, acc1[rb], 0, 0, 0);
        }
        #pragma unroll
        for (int rb = 0; rb < 4; ++rb)
            #pragma unroll
            for (int q = 0; q < 4; ++q) {
                const int e = rb * 16 + lk * 4 + q;
                const float hv = sspf(acc1[rb][q] + b1c);
                Ash[e * NF + (wcol ^ ((e & 7) << 3))] = f2bf(hv);
            }
        __syncthreads();

        // phase 2: wij = h @ W2
        f32x4 acc2[4] = {};
        #pragma unroll
        for (int rb = 0; rb < 4; ++rb) {
            short8 a[4];
            #pragma unroll
            for (int kb = 0; kb < 4; ++kb) {
                const int e  = rb * 16 + lr;
                const int k0 = kb * 32 + lk * 8;
                a[kb] = *reinterpret_cast<const short8*>(
                    &Ash[e * NF + (k0 ^ ((e & 7) << 3))]);
            }
            #pragma unroll
            for (int kb = 0; kb < 4; ++kb)
                acc2[rb] = __builtin_amdgcn_mfma_f32_16x16x32_bf16(
                    a[kb], b2fr[kb], acc2[rb], 0, 0, 0);
        }
        __syncthreads();            // h reads done -> Ash reusable

        // stage g = yf[j] rows: 4096 uints
        #pragma unroll
        for (int u = 0; u < 8; ++u) {
            const int tt = u * 512 + tid;
            const int slot = tt >> 6, cp = tt & 63;
            reinterpret_cast<unsigned*>(Ash)[tt] =
                reinterpret_cast<const unsigned*>(yf)[(jo_s[slot] >> 1) + cp];
        }
        __syncthreads();

        // per-thread: M write (x-side) + atomic (y-side, VALID slots only)
        #pragma unroll
        for (int rb = 0; rb < 4; ++rb)
            #pragma unroll
            for (int q = 0; q < 4; ++q) {
                const int e = rb * 16 + lk * 4 + q;
                const float wv = (acc2[rb][q] + b2c) * rc_s[e];
                const float g  = bf2f(Ash[e * NF + wcol]);
                M_s[e * 137 + wcol] = f2bf(wv * g);
                if (e < cnt) {                       // <-- the fix
                    const int oi = ni_s[e] - n0;
                    const float xo = bf2f(xown[oi * NF + wcol]);
                    unsafeAtomicAdd(&conv_y[(size_t)jo_s[e] + wcol], xo * wv);
                }
            }
        __syncthreads();

        // phase 3: accS += S @ M  (selector one-hot)
        #pragma unroll
        for (int kb2 = 0; kb2 < 2; ++kb2) {
            short8 bm;
            #pragma unroll
            for (int j = 0; j < 8; ++j)
                bm[j] = (short)M_s[(kb2 * 32 + lk * 8 + j) * 137 + wcol];
            #pragma unroll
            for (int rb2 = 0; rb2 < 2; ++rb2) {
                const int node = n0 + rb2 * 16 + lr;
                short8 as;
                #pragma unroll
                for (int j = 0; j < 8; ++j)
                    as[j] = (ni_s[kb2 * 32 + lk * 8 + j] == node)
                            ? (short)0x3F80 : (short)0;
                accS[rb2] = __builtin_amdgcn_mfma_f32_16x16x32_bf16(
                    as, bm, accS[rb2], 0, 0, 0);
            }
        }
    }

    // conv_x rows [n0, n0+32): written once, plain stores
    #pragma unroll
    for (int rb2 = 0; rb2 < 2; ++rb2)
        #pragma unroll
        for (int q = 0; q < 4; ++q) {
            const int n = n0 + rb2 * 16 + lk * 4 + q;
            if (n < NN) conv_x[(size_t)n * NF + wcol] = accS[rb2][q];
        }
}

// ---------------------------------------------------------------------------
// Projection (persistent): out_bf16 = in @ W (bias-free) + zero conv_y
// ---------------------------------------------------------------------------
__global__ __launch_bounds__(256, 2)
void proj_mfma_kernel(const float* in0, const float* in1,
                      const float* __restrict__ W0, const float* __restrict__ W1p,
                      unsigned short* o0, unsigned short* o1,
                      float* __restrict__ conv_y, int N, int nTiles)
{
    const float* in = blockIdx.y ? in1 : in0;
    const float* W  = blockIdx.y ? W1p : W0;
    unsigned short* out = blockIdx.y ? o1 : o0;

    const int tid = threadIdx.x;
    const int l = tid & 63, w = tid >> 6;
    const int lr = l & 15, lk = l >> 4;
    const int wcol0 = w * 32;

    __shared__ unsigned short Ahi[64 * NF];

    short8 bfr[4][2];
    #pragma unroll
    for (int kb = 0; kb < 4; ++kb)
        #pragma unroll
        for (int cb = 0; cb < 2; ++cb) {
            const int col = wcol0 + cb * 16 + lr;
            #pragma unroll
            for (int j = 0; j < 8; ++j)
                bfr[kb][cb][j] = (short)f2bf(W[(size_t)(kb * 32 + lk * 8 + j) * NF + col]);
        }

    for (int tile = blockIdx.x; tile < nTiles; tile += gridDim.x) {
        const int n0 = tile * 64;
        __syncthreads();
        #pragma unroll
        for (int s = 0; s < 32; ++s) {
            const int t = s * 256 + tid;
            const int row = t >> 7, cc = t & (NF - 1);
            const float v = (n0 + row < N) ? in[(size_t)(n0 + row) * NF + cc] : 0.f;
            Ahi[row * NF + (cc ^ ((row & 7) << 3))] = f2bf(v);
        }
        // zero conv_y rows [n0+32*y, n0+32*y+32)
        {
            const float4 z = {0.f, 0.f, 0.f, 0.f};
            const int rbase = n0 + 32 * blockIdx.y;
            #pragma unroll
            for (int s = 0; s < 4; ++s) {
                const int t = s * 256 + tid;
                const int row = rbase + (t >> 5);
                if (row < N)
                    *reinterpret_cast<float4*>(&conv_y[(size_t)row * NF + (t & 31) * 4]) = z;
            }
        }
        __syncthreads();

        f32x4 acc[4][2] = {};
        #pragma unroll
        for (int rb = 0; rb < 4; ++rb) {
            short8 a[4];
            #pragma unroll
            for (int kb = 0; kb < 4; ++kb) {
                const int e  = rb * 16 + lr;
                const int k0 = kb * 32 + lk * 8;
                a[kb] = *reinterpret_cast<const short8*>(&Ahi[e * NF + (k0 ^ ((e & 7) << 3))]);
            }
            #pragma unroll
            for (int cb = 0; cb < 2; ++cb)
                #pragma unroll
                for (int kb = 0; kb < 4; ++kb)
                    acc[rb][cb] = __builtin_amdgcn_mfma_f32_16x16x32_bf16(
                        a[kb], bfr[kb][cb], acc[rb][cb], 0, 0, 0);
        }

        #pragma unroll
        for (int rb = 0; rb < 4; ++rb)
            #pragma unroll
            for (int cb = 0; cb < 2; ++cb) {
                const int col = wcol0 + cb * 16 + lr;
                #pragma unroll
                for (int q = 0; q < 4; ++q) {
                    const int n = n0 + rb * 16 + lk * 4 + q;
                    if (n < N) out[(size_t)n * NF + col] = f2bf(acc[rb][cb][q]);
                }
            }
    }
}

// ---------------------------------------------------------------------------
// Fused output MLP (persistent): out = ssp(conv @ W1 + b1) @ W2 + b2
// split-bf16 (hi/lo) A for near-fp32 precision.
// ---------------------------------------------------------------------------
__global__ __launch_bounds__(256, 2)
void out_fused_kernel(const float* conv0, const float* conv1,
                      const float* __restrict__ W10, const float* __restrict__ W11,
                      const float* __restrict__ b10, const float* __restrict__ b11,
                      const float* __restrict__ W20, const float* __restrict__ W21,
                      const float* __restrict__ b20, const float* __restrict__ b21,
                      float* o0, float* o1, int N, int nTiles)
{
    const float* in = blockIdx.y ? conv1 : conv0;
    const float* W1 = blockIdx.y ? W11 : W10;
    const float* b1 = blockIdx.y ? b11 : b10;
    const float* W2 = blockIdx.y ? W21 : W20;
    const float* b2 = blockIdx.y ? b21 : b20;
    float* out      = blockIdx.y ? o1  : o0;

    const int tid = threadIdx.x;
    const int l = tid & 63, w = tid >> 6;
    const int lr = l & 15, lk = l >> 4;
    const int wcol0 = w * 32;

    __shared__ unsigned short Ahi[64 * NF];
    __shared__ unsigned short Alo[64 * NF];

    short8 w1fr[4][2], w2fr[4][2];
    #pragma unroll
    for (int kb = 0; kb < 4; ++kb)
        #pragma unroll
        for (int cb = 0; cb < 2; ++cb) {
            const int col = wcol0 + cb * 16 + lr;
            #pragma unroll
            for (int j = 0; j < 8; ++j) {
                const size_t kk = (size_t)(kb * 32 + lk * 8 + j) * NF + col;
                w1fr[kb][cb][j] = (short)f2bf(W1[kk]);
                w2fr[kb][cb][j] = (short)f2bf(W2[kk]);
            }
        }
    const float b1c0 = b1[wcol0 + lr], b1c1 = b1[wcol0 + 16 + lr];
    const float b2c0 = b2[wcol0 + lr], b2c1 = b2[wcol0 + 16 + lr];

    for (int tile = blockIdx.x; tile < nTiles; tile += gridDim.x) {
        const int n0 = tile * 64;
        __syncthreads();
        #pragma unroll
        for (int s = 0; s < 32; ++s) {
            const int t = s * 256 + tid;
            const int row = t >> 7, cc = t & (NF - 1);
            const float v = (n0 + row < N) ? in[(size_t)(n0 + row) * NF + cc] : 0.f;
            const unsigned short hi = f2bf(v);
            const int idx = row * NF + (cc ^ ((row & 7) << 3));
            Ahi[idx] = hi;
            Alo[idx] = f2bf(v - bf2f(hi));
        }
        __syncthreads();

        f32x4 acc1[4][2] = {};
        #pragma unroll
        for (int rb = 0; rb < 4; ++rb) {
            short8 ah[4], al[4];
            #pragma unroll
            for (int kb = 0; kb < 4; ++kb) {
                const int e  = rb * 16 + lr;
                const int k0 = kb * 32 + lk * 8;
                const int idx = e * NF + (k0 ^ ((e & 7) << 3));
                ah[kb] = *reinterpret_cast<const short8*>(&Ahi[idx]);
                al[kb] = *reinterpret_cast<const short8*>(&Alo[idx]);
            }
            #pragma unroll
            for (int cb = 0; cb < 2; ++cb)
                #pragma unroll
                for (int kb = 0; kb < 4; ++kb) {
                    acc1[rb][cb] = __builtin_amdgcn_mfma_f32_16x16x32_bf16(
                        ah[kb], w1fr[kb][cb], acc1[rb][cb], 0, 0, 0);
                    acc1[rb][cb] = __builtin_amdgcn_mfma_f32_16x16x32_bf16(
                        al[kb], w1fr[kb][cb], acc1[rb][cb], 0, 0, 0);
                }
        }
        __syncthreads();

        #pragma unroll
        for (int rb = 0; rb < 4; ++rb)
            #pragma unroll
            for (int cb = 0; cb < 2; ++cb) {
                const int col = wcol0 + cb * 16 + lr;
                #pragma unroll
                for (int q = 0; q < 4; ++q) {
                    const int e = rb * 16 + lk * 4 + q;
                    const float hv = sspf(acc1[rb][cb][q] + (cb ? b1c1 : b1c0));
                    const unsigned short hi = f2bf(hv);
                    const int idx = e * NF + (col ^ ((e & 7) << 3));
                    Ahi[idx] = hi;
                    Alo[idx] = f2bf(hv - bf2f(hi));
                }
            }
        __syncthreads();

        f32x4 acc2[4][2] = {};
        #pragma unroll
        for (int rb = 0; rb < 4; ++rb) {
            short8 ah[4], al[4];
            #pragma unroll
            for (int kb = 0; kb < 4; ++kb) {
                const int e  = rb * 16 + lr;
                const int k0 = kb * 32 + lk * 8;
                const int idx = e * NF + (k0 ^ ((e & 7) << 3));
                ah[kb] = *reinterpret_cast<const short8*>(&Ahi[idx]);
                al[kb] = *reinterpret_cast<const short8*>(&Alo[idx]);
            }
            #pragma unroll
            for (int cb = 0; cb < 2; ++cb)
                #pragma unroll
                for (int kb = 0; kb < 4; ++kb) {
                    acc2[rb][cb] = __builtin_amdgcn_mfma_f32_16x16x32_bf16(
                        ah[kb], w2fr[kb][cb], acc2[rb][cb], 0, 0, 0);
                    acc2[rb][cb] = __builtin_amdgcn_mfma_f32_16x16x32_bf16(
                        al[kb], w2fr[kb][cb], acc2[rb][cb], 0, 0, 0);
                }
        }

        #pragma unroll
        for (int rb = 0; rb < 4; ++rb)
            #pragma unroll
            for (int cb = 0; cb < 2; ++cb) {
                const int col = wcol0 + cb * 16 + lr;
                #pragma unroll
                for (int q = 0; q < 4; ++q) {
                    const int n = n0 + rb * 16 + lk * 4 + q;
                    if (n < N)
                        out[(size_t)n * NF + col] = acc2[rb][cb][q] + (cb ? b2c1 : b2c0);
                }
            }
    }
}

extern "C" void kernel_launch(void* const* d_in, const int* in_sizes, int n_in,
                              void* d_out, int out_size, void* d_ws, size_t ws_size,
                              hipStream_t stream)
{
    const float* x    = (const float*)d_in[0];
    const float* y    = (const float*)d_in[1];
    const float* f_ij = (const float*)d_in[2];
    const float* rcut = (const float*)d_in[3];
    const int* idx_i  = (const int*)d_in[4];
    const int* idx_j  = (const int*)d_in[5];
    const float* W_in2f   = (const float*)d_in[6];
    const float* W_in2f_y = (const float*)d_in[7];
    const float* Wf1 = (const float*)d_in[8];
    const float* bf1 = (const float*)d_in[9];
    const float* Wf2 = (const float*)d_in[10];
    const float* bf2 = (const float*)d_in[11];
    const float* Wx1 = (const float*)d_in[12];
    const float* bx1 = (const float*)d_in[13];
    const float* Wx2 = (const float*)d_in[14];
    const float* bx2 = (const float*)d_in[15];
    const float* Wy1 = (const float*)d_in[16];
    const float* by1 = (const float*)d_in[17];
    const float* Wy2 = (const float*)d_in[18];
    const float* by2 = (const float*)d_in[19];

    const int N = in_sizes[0] / NF;
    const int E = in_sizes[4];
    const size_t NNF = (size_t)N * NF;

    unsigned short* xf = (unsigned short*)d_out;
    unsigned short* yf = xf + NNF;
    float* ox = (float*)d_out;
    float* oy = ox + NNF;

    // sort scratch in upper half of d_out (dead before out_fused writes)
    int* sb    = (int*)((char*)d_out + 4 * NNF);
    int* deg   = sb;
    int* loc   = sb + N;
    int* rowp  = sb + 2 * N;
    int* cur   = sb + 3 * N;
    int* parts = sb + 4 * N;          // 64 ints
    int* ord   = sb + 4 * N + 64;     // E ints

    float* conv_x = (float*)d_ws;
    float* conv_y = conv_x + NNF;

    const int NB = (N + 2047) / 2048;
    const int nodeTiles = (N + 63) / 64;
    const int passBlocks = (N + 31) / 32;

    hipMemsetAsync(deg, 0, (size_t)N * sizeof(int), stream);

    proj_mfma_kernel<<<dim3(1024, 2), 256, 0, stream>>>(
        x, y, W_in2f, W_in2f_y, xf, yf, conv_y, N, nodeTiles);

    hist1_kernel<<<1024, 256, 0, stream>>>(idx_i, deg, E);
    scanA1_kernel<<<NB, 256, 0, stream>>>(deg, loc, parts, N);
    scanB1_kernel<<<1, 64, 0, stream>>>(parts, NB);
    scanC1_kernel<<<128, 256, 0, stream>>>(loc, parts, rowp, cur, N);
    scatter1_kernel<<<1024, 256, 0, stream>>>(idx_i, cur, ord, E);

    edge_hybrid_kernel<<<passBlocks, 512, 0, stream>>>(
        f_ij, rcut, idx_i, idx_j, Wf1, bf1, Wf2, bf2, xf, yf,
        ord, rowp, conv_x, conv_y, N, E);

    out_fused_kernel<<<dim3(1024, 2), 256, 0, stream>>>(
        conv_x, conv_y, Wx1, Wy1, bx1, by1, Wx2, Wy2, bx2, by2,
        ox, oy, N, nodeTiles);
}

// Round 13
// 745.386 us; speedup vs baseline: 10.7368x; 1.3311x over previous
//
#include <hip/hip_runtime.h>
#include <hip/hip_bf16.h>

#define NF 128
#define RBF 20

using short8 = __attribute__((ext_vector_type(8))) short;
using half8  = __attribute__((ext_vector_type(8))) _Float16;
using f32x4  = __attribute__((ext_vector_type(4))) float;

__device__ __forceinline__ float sspf(float v) {
    // softplus(v) - ln2 via HW exp/log: max(v,0) + log(1+exp(-|v|)) - ln2
    const float t = __expf(-fabsf(v));
    return fmaxf(v, 0.f) + __logf(1.f + t) - 0.69314718055994531f;
}
__device__ __forceinline__ unsigned short f2bf(float f) {
    union { float f; unsigned u; } v; v.f = f;
    unsigned r = v.u + 0x7fffu + ((v.u >> 16) & 1u);
    return (unsigned short)(r >> 16);
}
__device__ __forceinline__ float bf2f(unsigned short s) {
    union { unsigned u; float f; } v; v.u = ((unsigned)s) << 16;
    return v.f;
}

// ---------------------------------------------------------------------------
// Counting sort by idx_i only. (unchanged)
// ---------------------------------------------------------------------------
__global__ void hist1_kernel(const int* __restrict__ idx, int* __restrict__ deg, int E)
{
    for (int e = blockIdx.x * blockDim.x + threadIdx.x; e < E;
         e += gridDim.x * blockDim.x)
        atomicAdd(&deg[idx[e]], 1);
}

__global__ void scanA1_kernel(const int* __restrict__ deg, int* __restrict__ loc,
                              int* __restrict__ parts, int NN)
{
    const int tid = threadIdx.x;
    const int base = blockIdx.x * 2048;
    __shared__ int tsum[256];
    int v[8]; int s = 0;
    #pragma unroll
    for (int r = 0; r < 8; ++r) {
        const int idx = base + tid * 8 + r;
        v[r] = (idx < NN) ? deg[idx] : 0;
        s += v[r];
    }
    tsum[tid] = s;
    __syncthreads();
    #pragma unroll
    for (int d = 1; d < 256; d <<= 1) {
        const int add = (tid >= d) ? tsum[tid - d] : 0;
        __syncthreads();
        tsum[tid] += add;
        __syncthreads();
    }
    int run = tsum[tid] - s;
    #pragma unroll
    for (int r = 0; r < 8; ++r) {
        const int idx = base + tid * 8 + r;
        if (idx < NN) loc[idx] = run;
        run += v[r];
    }
    if (tid == 0) parts[blockIdx.x] = tsum[255];
}

__global__ void scanB1_kernel(int* __restrict__ parts, int NB)
{
    __shared__ int p[64];
    const int t = threadIdx.x;
    p[t] = (t < NB) ? parts[t] : 0;
    __syncthreads();
    #pragma unroll
    for (int d = 1; d < 64; d <<= 1) {
        const int add = (t >= d) ? p[t - d] : 0;
        __syncthreads();
        p[t] += add;
        __syncthreads();
    }
    parts[t] = (t > 0) ? p[t - 1] : 0;
}

__global__ void scanC1_kernel(const int* __restrict__ loc, const int* __restrict__ parts,
                              int* __restrict__ rowp, int* __restrict__ cur, int NN)
{
    for (int i = blockIdx.x * blockDim.x + threadIdx.x; i < NN;
         i += gridDim.x * blockDim.x) {
        const int v = loc[i] + parts[i >> 11];
        rowp[i] = v;
        cur[i]  = v;
    }
}

__global__ void scatter1_kernel(const int* __restrict__ idx, int* __restrict__ cur,
                                int* __restrict__ ord, int E)
{
    for (int e = blockIdx.x * blockDim.x + threadIdx.x; e < E;
         e += gridDim.x * blockDim.x) {
        const int p = atomicAdd(&cur[idx[e]], 1);
        ord[p] = e;
    }
}

// ---------------------------------------------------------------------------
// Hybrid edge kernel (512 thr = 8 waves, 16 cols/wave). Block owns 32 nodes
// (i-sorted). f16 MFMA pipeline:
//   phase1: h = ssp(f @ W1 + b1)     (f staged in M_s alias, K padded to 32)
//   phase2: wij = h @ W2 (+b2 later)
//   g = yf[j] rows staged (stride 136, conflict-spread)
//   per-thread: M = f16(wv*g) -> M_s; y-side fp32 atomics (valid slots only)
//   phase3: accS += S @ M (one-hot selector) -> conv_x plain stores
// ---------------------------------------------------------------------------
__global__ __launch_bounds__(512, 2)
void edge_hybrid_kernel(const float* __restrict__ f_ij,
                        const float* __restrict__ rcut,
                        const int* __restrict__ idx_i,
                        const int* __restrict__ idx_j,
                        const float* __restrict__ Wf1,
                        const float* __restrict__ bf1,
                        const float* __restrict__ Wf2,
                        const float* __restrict__ bf2v,
                        const _Float16* __restrict__ xf,
                        const _Float16* __restrict__ yf,
                        const int* __restrict__ ord,
                        const int* __restrict__ rowp,
                        float* __restrict__ conv_x,
                        float* __restrict__ conv_y,
                        int NN, int E)
{
    const int tid = threadIdx.x;
    const int l = tid & 63, w = tid >> 6;
    const int lr = l & 15, lk = l >> 4;
    const int wcol = w * 16 + lr;

    __shared__ _Float16 M_s[64 * 137];     // 17.5 KB; first 64*40 aliases f-staging
    __shared__ _Float16 Ash[64 * 136];     // 17.4 KB: h (stride128+XOR) then g (stride136)
    __shared__ _Float16 xown[32 * 136];    // 8.7 KB, stride 136
    __shared__ int ni_s[64];
    __shared__ int jo_s[64];
    __shared__ float rc_s[64];

    _Float16* fst = M_s;                   // f staging, stride 40

    // persistent weight fragments (16 cols per wave), f16
    half8 b1fr;
    #pragma unroll
    for (int j = 0; j < 8; ++j) {
        const int k = lk * 8 + j;
        b1fr[j] = (k < RBF) ? (_Float16)Wf1[k * NF + wcol] : (_Float16)0.f;
    }
    half8 b2fr[4];
    #pragma unroll
    for (int kb = 0; kb < 4; ++kb)
        #pragma unroll
        for (int j = 0; j < 8; ++j)
            b2fr[kb][j] = (_Float16)Wf2[(size_t)(kb * 32 + lk * 8 + j) * NF + wcol];
    const float b1c = bf1[wcol];
    const float b2c = bf2v[wcol];

    const int n0 = blockIdx.x * 32;
    const int eb = rowp[n0];
    const int ee = (n0 + 32 < NN) ? rowp[n0 + 32] : E;
    const int nt = (ee - eb + 63) >> 6;

    // stage own xf rows [n0, n0+32): 2048 uints, stride 136
    #pragma unroll
    for (int u = 0; u < 4; ++u) {
        const int tt = u * 512 + tid;
        const int row = tt >> 6, cp = tt & 63;
        unsigned v = 0;
        if (n0 + row < NN)
            v = reinterpret_cast<const unsigned*>(xf)[(size_t)(n0 + row) * 64 + cp];
        *reinterpret_cast<unsigned*>(&xown[row * 136 + cp * 2]) = v;
    }

    f32x4 accS[2] = {};    // nodes [n0+rb2*16 ...], col wcol

    for (int t = 0; t < nt; ++t) {
        const int p0 = eb + t * 64;
        const int cnt = ee - p0;             // valid slots this tile
        __syncthreads();

        if (tid < 64) {
            const int p = p0 + tid;
            const bool val = p < ee;
            const int e = val ? ord[p] : 0;
            ni_s[tid] = val ? idx_i[e] : -1;
            jo_s[tid] = val ? idx_j[e] * NF : 0;
            rc_s[tid] = val ? rcut[e] : 0.f;
        }
        #pragma unroll
        for (int s4 = 0; s4 < 4; ++s4) {
            const int tt = s4 * 512 + tid;
            const int row = tt >> 5, k = tt & 31;
            const int p = p0 + row;
            float v = 0.f;
            if (k < RBF && p < ee) v = f_ij[(size_t)ord[p] * RBF + k];
            fst[row * 40 + k] = (_Float16)v;
        }
        __syncthreads();

        // phase 1: h = ssp(f @ W1 + b1)
        f32x4 acc1[4] = {};
        #pragma unroll
        for (int rb = 0; rb < 4; ++rb) {
            const half8 a = *reinterpret_cast<const half8*>(
                &fst[(rb * 16 + lr) * 40 + lk * 8]);
            acc1[rb] = __builtin_amdgcn_mfma_f32_16x16x32_f16(a, b1fr, acc1[rb], 0, 0, 0);
        }
        #pragma unroll
        for (int rb = 0; rb < 4; ++rb)
            #pragma unroll
            for (int q = 0; q < 4; ++q) {
                const int e = rb * 16 + lk * 4 + q;
                const float hv = sspf(acc1[rb][q] + b1c);
                Ash[e * NF + (wcol ^ ((e & 7) << 3))] = (_Float16)hv;
            }
        __syncthreads();

        // phase 2: wij = h @ W2  (f dead after phase-1 reads)
        f32x4 acc2[4] = {};
        #pragma unroll
        for (int rb = 0; rb < 4; ++rb) {
            half8 a[4];
            #pragma unroll
            for (int kb = 0; kb < 4; ++kb) {
                const int e  = rb * 16 + lr;
                const int k0 = kb * 32 + lk * 8;
                a[kb] = *reinterpret_cast<const half8*>(
                    &Ash[e * NF + (k0 ^ ((e & 7) << 3))]);
            }
            #pragma unroll
            for (int kb = 0; kb < 4; ++kb)
                acc2[rb] = __builtin_amdgcn_mfma_f32_16x16x32_f16(
                    a[kb], b2fr[kb], acc2[rb], 0, 0, 0);
        }
        __syncthreads();            // h reads done -> Ash reusable for g

        // stage g = yf[j] rows: 4096 uints, stride 136
        #pragma unroll
        for (int u = 0; u < 8; ++u) {
            const int tt = u * 512 + tid;
            const int slot = tt >> 6, cp = tt & 63;
            const unsigned v =
                reinterpret_cast<const unsigned*>(yf)[(jo_s[slot] >> 1) + cp];
            *reinterpret_cast<unsigned*>(&Ash[slot * 136 + cp * 2]) = v;
        }
        __syncthreads();

        // per-thread: M write (x-side) + atomic (y-side, valid slots only)
        #pragma unroll
        for (int rb = 0; rb < 4; ++rb)
            #pragma unroll
            for (int q = 0; q < 4; ++q) {
                const int e = rb * 16 + lk * 4 + q;
                const float wv = (acc2[rb][q] + b2c) * rc_s[e];
                const float g  = (float)Ash[e * 136 + wcol];
                M_s[e * 137 + wcol] = (_Float16)(wv * g);
                if (e < cnt) {
                    const int oi = ni_s[e] - n0;
                    const float xo = (float)xown[oi * 136 + wcol];
                    unsafeAtomicAdd(&conv_y[(size_t)jo_s[e] + wcol], xo * wv);
                }
            }
        __syncthreads();

        // phase 3: accS += S @ M  (selector one-hot)
        #pragma unroll
        for (int kb2 = 0; kb2 < 2; ++kb2) {
            half8 bm;
            int nn[8];
            #pragma unroll
            for (int j = 0; j < 8; ++j) {
                bm[j] = M_s[(kb2 * 32 + lk * 8 + j) * 137 + wcol];
                nn[j] = ni_s[kb2 * 32 + lk * 8 + j];
            }
            #pragma unroll
            for (int rb2 = 0; rb2 < 2; ++rb2) {
                const int node = n0 + rb2 * 16 + lr;
                half8 as;
                #pragma unroll
                for (int j = 0; j < 8; ++j)
                    as[j] = (nn[j] == node) ? (_Float16)1.f : (_Float16)0.f;
                accS[rb2] = __builtin_amdgcn_mfma_f32_16x16x32_f16(
                    as, bm, accS[rb2], 0, 0, 0);
            }
        }
    }

    // conv_x rows [n0, n0+32): written once, plain stores
    #pragma unroll
    for (int rb2 = 0; rb2 < 2; ++rb2)
        #pragma unroll
        for (int q = 0; q < 4; ++q) {
            const int n = n0 + rb2 * 16 + lk * 4 + q;
            if (n < NN) conv_x[(size_t)n * NF + wcol] = accS[rb2][q];
        }
}

// ---------------------------------------------------------------------------
// Projection (persistent, f16): out_f16 = in @ W (bias-free) + zero conv_y
// ---------------------------------------------------------------------------
__global__ __launch_bounds__(256, 2)
void proj_mfma_kernel(const float* in0, const float* in1,
                      const float* __restrict__ W0, const float* __restrict__ W1p,
                      _Float16* o0, _Float16* o1,
                      float* __restrict__ conv_y, int N, int nTiles)
{
    const float* in = blockIdx.y ? in1 : in0;
    const float* W  = blockIdx.y ? W1p : W0;
    _Float16* out   = blockIdx.y ? o1 : o0;

    const int tid = threadIdx.x;
    const int l = tid & 63, w = tid >> 6;
    const int lr = l & 15, lk = l >> 4;
    const int wcol0 = w * 32;

    __shared__ _Float16 Ahi[64 * NF];

    half8 bfr[4][2];
    #pragma unroll
    for (int kb = 0; kb < 4; ++kb)
        #pragma unroll
        for (int cb = 0; cb < 2; ++cb) {
            const int col = wcol0 + cb * 16 + lr;
            #pragma unroll
            for (int j = 0; j < 8; ++j)
                bfr[kb][cb][j] = (_Float16)W[(size_t)(kb * 32 + lk * 8 + j) * NF + col];
        }

    for (int tile = blockIdx.x; tile < nTiles; tile += gridDim.x) {
        const int n0 = tile * 64;
        __syncthreads();
        #pragma unroll
        for (int s = 0; s < 32; ++s) {
            const int t = s * 256 + tid;
            const int row = t >> 7, cc = t & (NF - 1);
            const float v = (n0 + row < N) ? in[(size_t)(n0 + row) * NF + cc] : 0.f;
            Ahi[row * NF + (cc ^ ((row & 7) << 3))] = (_Float16)v;
        }
        // zero conv_y rows [n0+32*y, n0+32*y+32)
        {
            const float4 z = {0.f, 0.f, 0.f, 0.f};
            const int rbase = n0 + 32 * blockIdx.y;
            #pragma unroll
            for (int s = 0; s < 4; ++s) {
                const int t = s * 256 + tid;
                const int row = rbase + (t >> 5);
                if (row < N)
                    *reinterpret_cast<float4*>(&conv_y[(size_t)row * NF + (t & 31) * 4]) = z;
            }
        }
        __syncthreads();

        f32x4 acc[4][2] = {};
        #pragma unroll
        for (int rb = 0; rb < 4; ++rb) {
            half8 a[4];
            #pragma unroll
            for (int kb = 0; kb < 4; ++kb) {
                const int e  = rb * 16 + lr;
                const int k0 = kb * 32 + lk * 8;
                a[kb] = *reinterpret_cast<const half8*>(&Ahi[e * NF + (k0 ^ ((e & 7) << 3))]);
            }
            #pragma unroll
            for (int cb = 0; cb < 2; ++cb)
                #pragma unroll
                for (int kb = 0; kb < 4; ++kb)
                    acc[rb][cb] = __builtin_amdgcn_mfma_f32_16x16x32_f16(
                        a[kb], bfr[kb][cb], acc[rb][cb], 0, 0, 0);
        }

        #pragma unroll
        for (int rb = 0; rb < 4; ++rb)
            #pragma unroll
            for (int cb = 0; cb < 2; ++cb) {
                const int col = wcol0 + cb * 16 + lr;
                #pragma unroll
                for (int q = 0; q < 4; ++q) {
                    const int n = n0 + rb * 16 + lk * 4 + q;
                    if (n < N) out[(size_t)n * NF + col] = (_Float16)acc[rb][cb][q];
                }
            }
    }
}

// ---------------------------------------------------------------------------
// Fused output MLP (persistent): out = ssp(conv @ W1 + b1) @ W2 + b2
// split-bf16 (hi/lo) A for near-fp32 precision. (structure unchanged)
// ---------------------------------------------------------------------------
__global__ __launch_bounds__(256, 2)
void out_fused_kernel(const float* conv0, const float* conv1,
                      const float* __restrict__ W10, const float* __restrict__ W11,
                      const float* __restrict__ b10, const float* __restrict__ b11,
                      const float* __restrict__ W20, const float* __restrict__ W21,
                      const float* __restrict__ b20, const float* __restrict__ b21,
                      float* o0, float* o1, int N, int nTiles)
{
    const float* in = blockIdx.y ? conv1 : conv0;
    const float* W1 = blockIdx.y ? W11 : W10;
    const float* b1 = blockIdx.y ? b11 : b10;
    const float* W2 = blockIdx.y ? W21 : W20;
    const float* b2 = blockIdx.y ? b21 : b20;
    float* out      = blockIdx.y ? o1  : o0;

    const int tid = threadIdx.x;
    const int l = tid & 63, w = tid >> 6;
    const int lr = l & 15, lk = l >> 4;
    const int wcol0 = w * 32;

    __shared__ unsigned short Ahi[64 * NF];
    __shared__ unsigned short Alo[64 * NF];

    short8 w1fr[4][2], w2fr[4][2];
    #pragma unroll
    for (int kb = 0; kb < 4; ++kb)
        #pragma unroll
        for (int cb = 0; cb < 2; ++cb) {
            const int col = wcol0 + cb * 16 + lr;
            #pragma unroll
            for (int j = 0; j < 8; ++j) {
                const size_t kk = (size_t)(kb * 32 + lk * 8 + j) * NF + col;
                w1fr[kb][cb][j] = (short)f2bf(W1[kk]);
                w2fr[kb][cb][j] = (short)f2bf(W2[kk]);
            }
        }
    const float b1c0 = b1[wcol0 + lr], b1c1 = b1[wcol0 + 16 + lr];
    const float b2c0 = b2[wcol0 + lr], b2c1 = b2[wcol0 + 16 + lr];

    for (int tile = blockIdx.x; tile < nTiles; tile += gridDim.x) {
        const int n0 = tile * 64;
        __syncthreads();
        #pragma unroll
        for (int s = 0; s < 32; ++s) {
            const int t = s * 256 + tid;
            const int row = t >> 7, cc = t & (NF - 1);
            const float v = (n0 + row < N) ? in[(size_t)(n0 + row) * NF + cc] : 0.f;
            const unsigned short hi = f2bf(v);
            const int idx = row * NF + (cc ^ ((row & 7) << 3));
            Ahi[idx] = hi;
            Alo[idx] = f2bf(v - bf2f(hi));
        }
        __syncthreads();

        f32x4 acc1[4][2] = {};
        #pragma unroll
        for (int rb = 0; rb < 4; ++rb) {
            short8 ah[4], al[4];
            #pragma unroll
            for (int kb = 0; kb < 4; ++kb) {
                const int e  = rb * 16 + lr;
                const int k0 = kb * 32 + lk * 8;
                const int idx = e * NF + (k0 ^ ((e & 7) << 3));
                ah[kb] = *reinterpret_cast<const short8*>(&Ahi[idx]);
                al[kb] = *reinterpret_cast<const short8*>(&Alo[idx]);
            }
            #pragma unroll
            for (int cb = 0; cb < 2; ++cb)
                #pragma unroll
                for (int kb = 0; kb < 4; ++kb) {
                    acc1[rb][cb] = __builtin_amdgcn_mfma_f32_16x16x32_bf16(
                        ah[kb], w1fr[kb][cb], acc1[rb][cb], 0, 0, 0);
                    acc1[rb][cb] = __builtin_amdgcn_mfma_f32_16x16x32_bf16(
                        al[kb], w1fr[kb][cb], acc1[rb][cb], 0, 0, 0);
                }
        }
        __syncthreads();

        #pragma unroll
        for (int rb = 0; rb < 4; ++rb)
            #pragma unroll
            for (int cb = 0; cb < 2; ++cb) {
                const int col = wcol0 + cb * 16 + lr;
                #pragma unroll
                for (int q = 0; q < 4; ++q) {
                    const int e = rb * 16 + lk * 4 + q;
                    const float hv = sspf(acc1[rb][cb][q] + (cb ? b1c1 : b1c0));
                    const unsigned short hi = f2bf(hv);
                    const int idx = e * NF + (col ^ ((e & 7) << 3));
                    Ahi[idx] = hi;
                    Alo[idx] = f2bf(hv - bf2f(hi));
                }
            }
        __syncthreads();

        f32x4 acc2[4][2] = {};
        #pragma unroll
        for (int rb = 0; rb < 4; ++rb) {
            short8 ah[4], al[4];
            #pragma unroll
            for (int kb = 0; kb < 4; ++kb) {
                const int e  = rb * 16 + lr;
                const int k0 = kb * 32 + lk * 8;
                const int idx = e * NF + (k0 ^ ((e & 7) << 3));
                ah[kb] = *reinterpret_cast<const short8*>(&Ahi[idx]);
                al[kb] = *reinterpret_cast<const short8*>(&Alo[idx]);
            }
            #pragma unroll
            for (int cb = 0; cb < 2; ++cb)
                #pragma unroll
                for (int kb = 0; kb < 4; ++kb) {
                    acc2[rb][cb] = __builtin_amdgcn_mfma_f32_16x16x32_bf16(
                        ah[kb], w2fr[kb][cb], acc2[rb][cb], 0, 0, 0);
                    acc2[rb][cb] = __builtin_amdgcn_mfma_f32_16x16x32_bf16(
                        al[kb], w2fr[kb][cb], acc2[rb][cb], 0, 0, 0);
                }
        }

        #pragma unroll
        for (int rb = 0; rb < 4; ++rb)
            #pragma unroll
            for (int cb = 0; cb < 2; ++cb) {
                const int col = wcol0 + cb * 16 + lr;
                #pragma unroll
                for (int q = 0; q < 4; ++q) {
                    const int n = n0 + rb * 16 + lk * 4 + q;
                    if (n < N)
                        out[(size_t)n * NF + col] = acc2[rb][cb][q] + (cb ? b2c1 : b2c0);
                }
            }
    }
}

extern "C" void kernel_launch(void* const* d_in, const int* in_sizes, int n_in,
                              void* d_out, int out_size, void* d_ws, size_t ws_size,
                              hipStream_t stream)
{
    const float* x    = (const float*)d_in[0];
    const float* y    = (const float*)d_in[1];
    const float* f_ij = (const float*)d_in[2];
    const float* rcut = (const float*)d_in[3];
    const int* idx_i  = (const int*)d_in[4];
    const int* idx_j  = (const int*)d_in[5];
    const float* W_in2f   = (const float*)d_in[6];
    const float* W_in2f_y = (const float*)d_in[7];
    const float* Wf1 = (const float*)d_in[8];
    const float* bf1 = (const float*)d_in[9];
    const float* Wf2 = (const float*)d_in[10];
    const float* bf2 = (const float*)d_in[11];
    const float* Wx1 = (const float*)d_in[12];
    const float* bx1 = (const float*)d_in[13];
    const float* Wx2 = (const float*)d_in[14];
    const float* bx2 = (const float*)d_in[15];
    const float* Wy1 = (const float*)d_in[16];
    const float* by1 = (const float*)d_in[17];
    const float* Wy2 = (const float*)d_in[18];
    const float* by2 = (const float*)d_in[19];

    const int N = in_sizes[0] / NF;
    const int E = in_sizes[4];
    const size_t NNF = (size_t)N * NF;

    _Float16* xf = (_Float16*)d_out;
    _Float16* yf = xf + NNF;
    float* ox = (float*)d_out;
    float* oy = ox + NNF;

    // sort scratch in upper half of d_out (dead before out_fused writes)
    int* sb    = (int*)((char*)d_out + 4 * NNF);
    int* deg   = sb;
    int* loc   = sb + N;
    int* rowp  = sb + 2 * N;
    int* cur   = sb + 3 * N;
    int* parts = sb + 4 * N;          // 64 ints
    int* ord   = sb + 4 * N + 64;     // E ints

    float* conv_x = (float*)d_ws;
    float* conv_y = conv_x + NNF;

    const int NB = (N + 2047) / 2048;
    const int nodeTiles = (N + 63) / 64;
    const int passBlocks = (N + 31) / 32;

    hipMemsetAsync(deg, 0, (size_t)N * sizeof(int), stream);

    proj_mfma_kernel<<<dim3(1024, 2), 256, 0, stream>>>(
        x, y, W_in2f, W_in2f_y, xf, yf, conv_y, N, nodeTiles);

    hist1_kernel<<<1024, 256, 0, stream>>>(idx_i, deg, E);
    scanA1_kernel<<<NB, 256, 0, stream>>>(deg, loc, parts, N);
    scanB1_kernel<<<1, 64, 0, stream>>>(parts, NB);
    scanC1_kernel<<<128, 256, 0, stream>>>(loc, parts, rowp, cur, N);
    scatter1_kernel<<<1024, 256, 0, stream>>>(idx_i, cur, ord, E);

    edge_hybrid_kernel<<<passBlocks, 512, 0, stream>>>(
        f_ij, rcut, idx_i, idx_j, Wf1, bf1, Wf2, bf2, xf, yf,
        ord, rowp, conv_x, conv_y, N, E);

    out_fused_kernel<<<dim3(1024, 2), 256, 0, stream>>>(
        conv_x, conv_y, Wx1, Wy1, bx1, by1, Wx2, Wy2, bx2, by2,
        ox, oy, N, nodeTiles);
}